// Round 10
// baseline (185.952 us; speedup 1.0000x reference)
//
#include <hip/hip_runtime.h>
#include <hip/hip_bf16.h>
#include <cstdint>
#include <cstddef>

// Problem constants
#define B_    8
#define H_    8
#define BH_   64
#define S_    976     // sequence length
#define SP_   992     // V^T row stride (shorts)
#define D_    64      // head dim
#define DM_   512     // d_model
#define L_    16      // max_len
#define H2_   61      // pooled conv height / q-tiles
#define KW_   25      // conv taps
#define EFF_  32      // effective (conv+pool) taps
#define XOFF  3997696 // x output elements = 8*976*512; attn follows
#define OSTR  68      // olds row stride (floats)

typedef __attribute__((ext_vector_type(8))) short bf16x8;
typedef __attribute__((ext_vector_type(4))) short bf16x4;
typedef __attribute__((ext_vector_type(4))) float f32x4;

__device__ __forceinline__ unsigned short f2bfu(float f) {
    union { float f; unsigned u; } v; v.f = f;
    unsigned u = v.u;
    u += 0x7fffu + ((u >> 16) & 1u);   // round-to-nearest-even
    return (unsigned short)(u >> 16);
}
__device__ __forceinline__ unsigned packbf(float a, float b) {
    return (unsigned)f2bfu(a) | ((unsigned)f2bfu(b) << 16);
}
__device__ __forceinline__ float bflo(unsigned u) {
    union { unsigned u; float f; } v; v.u = u << 16; return v.f;
}
__device__ __forceinline__ float bfhi(unsigned u) {
    union { unsigned u; float f; } v; v.u = u & 0xffff0000u; return v.f;
}

// K=16 bf16 MFMA: A row = lane&15, k = (lane>>4)*4+i; C/D col=lane&15,
// row=(lane>>4)*4+i  (verified correct end-to-end in round 7)
__device__ __forceinline__ f32x4 mfma16(bf16x4 a, bf16x4 b, f32x4 c) {
#if __has_builtin(__builtin_amdgcn_mfma_f32_16x16x16bf16_1k)
    return __builtin_amdgcn_mfma_f32_16x16x16bf16_1k(a, b, c, 0, 0, 0);
#else
    asm volatile("v_mfma_f32_16x16x16_bf16 %0, %1, %2, %0"
                 : "+v"(c) : "v"(a), "v"(b));
    return c;
#endif
}

// ---------------------------------------------------------------------------
// Kernel 1: projection with inline conv+pool weight folding (unchanged, R7).
// ---------------------------------------------------------------------------
__global__ __launch_bounds__(256) void proj_kernel(
    const float* __restrict__ qin, const float* __restrict__ kin,
    const float* __restrict__ vin, const float* __restrict__ wq,
    const float* __restrict__ wk, const float* __restrict__ wv,
    short* __restrict__ qws, short* __restrict__ kws, short* __restrict__ vtws) {
    __shared__ float xl[536 * L_];   // 34.3 KB
    __shared__ float wl[32 * 32];    // 4 KB folded weights
    int blk = blockIdx.x;            // grid = 3*8*16 = 384
    int cg  = blk & 15;
    int b   = (blk >> 4) & 7;
    int tz  = blk >> 7;
    const float* x    = (tz == 0) ? qin : (tz == 1) ? kin : vin;
    const float* wsrc = (tz == 0) ? wq  : (tz == 1) ? wk  : wv;

    const float4* xb4 = (const float4*)(x + b * DM_ * L_);
    float4* xl4 = (float4*)xl;
    for (int i = threadIdx.x; i < DM_ * L_ / 4; i += 256) xl4[i] = xb4[i];
    for (int i = DM_ * L_ + threadIdx.x; i < 536 * L_; i += 256) xl[i] = 0.f;

    for (int i = threadIdx.x; i < 1024; i += 256) {
        int ci = i >> 5;
        int t  = i & 31;
        int c  = cg * 32 + ci;
        int jlo = (t - 24 > 0) ? t - 24 : 0;
        int jhi = (t < 7) ? t : 7;
        float s = 0.f;
        for (int jj = jlo; jj <= jhi; ++jj) s += wsrc[c * KW_ + (t - jj)];
        wl[i] = s * 0.125f;
    }
    __syncthreads();

    int c_local = threadIdx.x >> 3;
    int plane   = threadIdx.x & 7;
    int c       = cg * 32 + c_local;
    float wreg[EFF_];
    #pragma unroll
    for (int i = 0; i < EFF_; ++i) wreg[i] = wl[c_local * 32 + i];

    for (int m = 0; m < 32; ++m) {
        int pg  = plane + 8 * m;
        int h2b = pg >> 4;
        int l   = pg & 15;
        float acc[4] = {0.f, 0.f, 0.f, 0.f};
        #pragma unroll
        for (int k = 0; k < 56; ++k) {
            float xv = xl[(h2b * 32 + k) * L_ + l];
            #pragma unroll
            for (int d = 0; d < 4; ++d) {
                int t = k - 8 * d;
                if (t >= 0 && t < EFF_) acc[d] = fmaf(xv, wreg[t], acc[d]);
            }
        }
        #pragma unroll
        for (int d = 0; d < 4; ++d) {
            int h2 = h2b * 4 + d;
            if (h2 < H2_) {
                int f    = c * S_ + h2 * L_ + l;
                int s    = f >> 9;
                int head = (f >> 6) & 7;
                int dh   = f & 63;
                int bh   = b * H_ + head;
                short bv = (short)f2bfu(acc[d]);
                if (tz == 0)      qws[((size_t)bh * S_ + s) * D_ + dh] = bv;
                else if (tz == 1) kws[((size_t)bh * S_ + s) * D_ + dh] = bv;
                else              vtws[((size_t)bh * D_ + dh) * SP_ + s] = bv;
            }
        }
    }
}

// ---------------------------------------------------------------------------
// Kernel 2: attention. One block per (bh, q-tile); 4 waves own key quarters
// (16/15/15/15 tiles). Pass A per tile, with explicit K/V register
// double-buffer prefetch (next tile's 6 loads issue BEFORE this tile's
// compute): QK^T (K=32, swapped) -> exp -> pack pp[ct] -> PV via K=16 MFMA
// consuming packed registers directly. No LDS in the loop. Pass B: burst of
// normalized NT attn stores from pp. Then olds combine + x epilogue.
// ---------------------------------------------------------------------------
__global__ __launch_bounds__(256) void attn_kernel(
    const short* __restrict__ qws, const short* __restrict__ kws,
    const short* __restrict__ vtws, const float* __restrict__ w_out,
    const float* __restrict__ b_out, float* __restrict__ out) {
    __shared__ float olds[3][16 * OSTR];      // 13 KB
    __shared__ float sums[4][16];

    int w    = threadIdx.x >> 6;
    int lane = threadIdx.x & 63;
    int l16  = lane & 15;
    int g    = lane >> 4;

    // XCD swizzle: xcd = blk%8 hosts bh in {xcd, xcd+8, ..., xcd+56}
    int blk = blockIdx.x;       // 0..3903
    int xcd = blk & 7;
    int j   = blk >> 3;         // 0..487
    int bh  = xcd + 8 * (j / H2_);
    int qt  = j % H2_;          // 0..60
    int s0  = qt * 16;

    int t0 = (w == 0) ? 0 : 16 + (w - 1) * 15;   // 0,16,31,46
    int nt = (w == 0) ? 16 : 15;

    const short* qb = qws + ((size_t)bh * S_ + s0 + l16) * D_ + g * 8;
    bf16x8 q0 = *(const bf16x8*)qb;
    bf16x8 q1 = *(const bf16x8*)(qb + 32);
    const short* kbase = kws + ((size_t)bh * S_ + l16) * D_ + g * 8;
    const short* vbase = vtws + ((size_t)bh * D_ + l16) * SP_ + g * 4;

    unsigned pp[16][2];         // packed bf16 exp-scores (static-indexed)
    f32x4 o0 = {0.f,0.f,0.f,0.f}, o1 = {0.f,0.f,0.f,0.f};
    f32x4 o2 = {0.f,0.f,0.f,0.f}, o3 = {0.f,0.f,0.f,0.f};
    float sa = 0.f, sb = 0.f, sc_ = 0.f, sd = 0.f;

    // prefetch registers (SSA-renamed each iteration)
    bf16x8 nk0, nk1;
    bf16x4 nv0, nv1, nv2, nv3;
    {
        const short* kb = kbase + (size_t)t0 * 16 * D_;
        nk0 = *(const bf16x8*)kb;
        nk1 = *(const bf16x8*)(kb + 32);
        const short* vb = vbase + t0 * 16;
        nv0 = *(const bf16x4*)(vb);
        nv1 = *(const bf16x4*)(vb + 16 * SP_);
        nv2 = *(const bf16x4*)(vb + 32 * SP_);
        nv3 = *(const bf16x4*)(vb + 48 * SP_);
    }

    #pragma unroll
    for (int ct = 0; ct < 16; ++ct) {
        if (ct < nt) {                        // wave-uniform
            bf16x8 k0 = nk0, k1 = nk1;
            bf16x4 v0 = nv0, v1 = nv1, v2 = nv2, v3 = nv3;
            if (ct + 1 < nt) {                // prefetch next tile FIRST
                int gt = t0 + ct + 1;
                const short* kb = kbase + (size_t)gt * 16 * D_;
                nk0 = *(const bf16x8*)kb;
                nk1 = *(const bf16x8*)(kb + 32);
                const short* vb = vbase + gt * 16;
                nv0 = *(const bf16x4*)(vb);
                nv1 = *(const bf16x4*)(vb + 16 * SP_);
                nv2 = *(const bf16x4*)(vb + 32 * SP_);
                nv3 = *(const bf16x4*)(vb + 48 * SP_);
            }
            f32x4 acc = {0.f, 0.f, 0.f, 0.f};
            acc = __builtin_amdgcn_mfma_f32_16x16x32_bf16(k0, q0, acc, 0, 0, 0);
            acc = __builtin_amdgcn_mfma_f32_16x16x32_bf16(k1, q1, acc, 0, 0, 0);
            float e0 = __expf(acc[0] * 0.125f);
            float e1 = __expf(acc[1] * 0.125f);
            float e2 = __expf(acc[2] * 0.125f);
            float e3 = __expf(acc[3] * 0.125f);
            sa += e0; sb += e1; sc_ += e2; sd += e3;
            unsigned u0 = packbf(e0, e1);
            unsigned u1 = packbf(e2, e3);
            pp[ct][0] = u0;
            pp[ct][1] = u1;
            union { uint2 u; bf16x4 v; } pc;
            pc.u.x = u0; pc.u.y = u1;
            o0 = mfma16(pc.v, v0, o0);
            o1 = mfma16(pc.v, v1, o1);
            o2 = mfma16(pc.v, v2, o2);
            o3 = mfma16(pc.v, v3, o3);
        }
    }
    float sum = (sa + sb) + (sc_ + sd);
    sum += __shfl_xor(sum, 16);
    sum += __shfl_xor(sum, 32);
    if (lane < 16) sums[w][l16] = sum;
    __syncthreads();
    float inv = 1.f / ((sums[0][l16] + sums[1][l16]) +
                       (sums[2][l16] + sums[3][l16]));

    // ---- pass B: dependence-free burst of normalized attn stores ----
    float* arow = out + XOFF + ((size_t)bh * S_ + s0 + l16) * S_;
    #pragma unroll
    for (int ct = 0; ct < 16; ++ct) {
        if (ct < nt) {
            unsigned u0 = pp[ct][0], u1 = pp[ct][1];
            f32x4 pv = { bflo(u0) * inv, bfhi(u0) * inv,
                         bflo(u1) * inv, bfhi(u1) * inv };
            __builtin_nontemporal_store(pv,
                (f32x4*)(arow + (t0 + ct) * 16 + g * 4));
        }
    }

    // ---- waves 0..2 publish raw partial O ----
    if (w != 3) {
        float* ob = &olds[w][0];
        #pragma unroll
        for (int i = 0; i < 4; ++i) {
            int q = g * 4 + i;
            ob[q * OSTR +  0 + l16] = o0[i];
            ob[q * OSTR + 16 + l16] = o1[i];
            ob[q * OSTR + 32 + l16] = o2[i];
            ob[q * OSTR + 48 + l16] = o3[i];
        }
    }
    __syncthreads();

    // ---- w3 combines, normalizes (deferred inv), writes x ----
    if (w == 3) {
        float wo = w_out[0], bo = b_out[0];
        int b = bh >> 3, hh = bh & 7;
        #pragma unroll
        for (int i = 0; i < 4; ++i) {
            int q = g * 4 + i;
            float invq = 1.f / ((sums[0][q] + sums[1][q]) +
                                (sums[2][q] + sums[3][q]));
            float s1 = invq * wo;
            float* xr = out + ((size_t)b * S_ + s0 + q) * DM_ + hh * D_ + l16;
            int o = q * OSTR + l16;
            xr[0]  = (o0[i] + olds[0][o +  0] + olds[1][o +  0] + olds[2][o +  0]) * s1 + bo;
            xr[16] = (o1[i] + olds[0][o + 16] + olds[1][o + 16] + olds[2][o + 16]) * s1 + bo;
            xr[32] = (o2[i] + olds[0][o + 32] + olds[1][o + 32] + olds[2][o + 32]) * s1 + bo;
            xr[48] = (o3[i] + olds[0][o + 48] + olds[1][o + 48] + olds[2][o + 48]) * s1 + bo;
        }
    }
}

// ---------------------------------------------------------------------------
extern "C" void kernel_launch(void* const* d_in, const int* in_sizes, int n_in,
                              void* d_out, int out_size, void* d_ws, size_t ws_size,
                              hipStream_t stream) {
    const float* q   = (const float*)d_in[0];
    const float* k   = (const float*)d_in[1];
    const float* v   = (const float*)d_in[2];
    const float* wq  = (const float*)d_in[3];
    const float* wk  = (const float*)d_in[4];
    const float* wv  = (const float*)d_in[5];
    const float* wo  = (const float*)d_in[6];
    const float* bo  = (const float*)d_in[7];

    char* ws = (char*)d_ws;
    short* qws  = (short*)(ws + 196608);
    short* kws  = qws + (size_t)BH_ * S_ * D_;
    short* vtws = kws + (size_t)BH_ * S_ * D_;

    proj_kernel<<<384, 256, 0, stream>>>(q, k, v, wq, wk, wv, qws, kws, vtws);
    attn_kernel<<<BH_ * H2_, 256, 0, stream>>>(qws, kws, vtws, wo, bo,
                                               (float*)d_out);
}

// Round 11
// 185.301 us; speedup vs baseline: 1.0035x; 1.0035x over previous
//
#include <hip/hip_runtime.h>
#include <hip/hip_bf16.h>
#include <cstdint>
#include <cstddef>

// Problem constants
#define B_    8
#define H_    8
#define BH_   64
#define S_    976     // sequence length
#define SP_   992     // V^T row stride (shorts)
#define D_    64      // head dim
#define DM_   512     // d_model
#define L_    16      // max_len
#define H2_   61      // pooled conv height / q-tiles
#define KW_   25      // conv taps
#define EFF_  32      // effective (conv+pool) taps
#define XOFF  3997696 // x output elements = 8*976*512; attn follows
#define OSTR  68      // olds row stride (floats)

typedef __attribute__((ext_vector_type(8))) short bf16x8;
typedef __attribute__((ext_vector_type(4))) short bf16x4;
typedef __attribute__((ext_vector_type(4))) float f32x4;

__device__ __forceinline__ unsigned short f2bfu(float f) {
    union { float f; unsigned u; } v; v.f = f;
    unsigned u = v.u;
    u += 0x7fffu + ((u >> 16) & 1u);   // round-to-nearest-even
    return (unsigned short)(u >> 16);
}
__device__ __forceinline__ unsigned packbf(float a, float b) {
    return (unsigned)f2bfu(a) | ((unsigned)f2bfu(b) << 16);
}
__device__ __forceinline__ float bflo(unsigned u) {
    union { unsigned u; float f; } v; v.u = u << 16; return v.f;
}
__device__ __forceinline__ float bfhi(unsigned u) {
    union { unsigned u; float f; } v; v.u = u & 0xffff0000u; return v.f;
}

// K=16 bf16 MFMA: A row = lane&15, k = (lane>>4)*4+i; C/D col=lane&15,
// row=(lane>>4)*4+i  (verified correct end-to-end in round 7)
__device__ __forceinline__ f32x4 mfma16(bf16x4 a, bf16x4 b, f32x4 c) {
#if __has_builtin(__builtin_amdgcn_mfma_f32_16x16x16bf16_1k)
    return __builtin_amdgcn_mfma_f32_16x16x16bf16_1k(a, b, c, 0, 0, 0);
#else
    asm volatile("v_mfma_f32_16x16x16_bf16 %0, %1, %2, %0"
                 : "+v"(c) : "v"(a), "v"(b));
    return c;
#endif
}

// ---------------------------------------------------------------------------
// Kernel 1: projection with inline conv+pool weight folding (unchanged, R7).
// ---------------------------------------------------------------------------
__global__ __launch_bounds__(256) void proj_kernel(
    const float* __restrict__ qin, const float* __restrict__ kin,
    const float* __restrict__ vin, const float* __restrict__ wq,
    const float* __restrict__ wk, const float* __restrict__ wv,
    short* __restrict__ qws, short* __restrict__ kws, short* __restrict__ vtws) {
    __shared__ float xl[536 * L_];   // 34.3 KB
    __shared__ float wl[32 * 32];    // 4 KB folded weights
    int blk = blockIdx.x;            // grid = 3*8*16 = 384
    int cg  = blk & 15;
    int b   = (blk >> 4) & 7;
    int tz  = blk >> 7;
    const float* x    = (tz == 0) ? qin : (tz == 1) ? kin : vin;
    const float* wsrc = (tz == 0) ? wq  : (tz == 1) ? wk  : wv;

    const float4* xb4 = (const float4*)(x + b * DM_ * L_);
    float4* xl4 = (float4*)xl;
    for (int i = threadIdx.x; i < DM_ * L_ / 4; i += 256) xl4[i] = xb4[i];
    for (int i = DM_ * L_ + threadIdx.x; i < 536 * L_; i += 256) xl[i] = 0.f;

    for (int i = threadIdx.x; i < 1024; i += 256) {
        int ci = i >> 5;
        int t  = i & 31;
        int c  = cg * 32 + ci;
        int jlo = (t - 24 > 0) ? t - 24 : 0;
        int jhi = (t < 7) ? t : 7;
        float s = 0.f;
        for (int jj = jlo; jj <= jhi; ++jj) s += wsrc[c * KW_ + (t - jj)];
        wl[i] = s * 0.125f;
    }
    __syncthreads();

    int c_local = threadIdx.x >> 3;
    int plane   = threadIdx.x & 7;
    int c       = cg * 32 + c_local;
    float wreg[EFF_];
    #pragma unroll
    for (int i = 0; i < EFF_; ++i) wreg[i] = wl[c_local * 32 + i];

    for (int m = 0; m < 32; ++m) {
        int pg  = plane + 8 * m;
        int h2b = pg >> 4;
        int l   = pg & 15;
        float acc[4] = {0.f, 0.f, 0.f, 0.f};
        #pragma unroll
        for (int k = 0; k < 56; ++k) {
            float xv = xl[(h2b * 32 + k) * L_ + l];
            #pragma unroll
            for (int d = 0; d < 4; ++d) {
                int t = k - 8 * d;
                if (t >= 0 && t < EFF_) acc[d] = fmaf(xv, wreg[t], acc[d]);
            }
        }
        #pragma unroll
        for (int d = 0; d < 4; ++d) {
            int h2 = h2b * 4 + d;
            if (h2 < H2_) {
                int f    = c * S_ + h2 * L_ + l;
                int s    = f >> 9;
                int head = (f >> 6) & 7;
                int dh   = f & 63;
                int bh   = b * H_ + head;
                short bv = (short)f2bfu(acc[d]);
                if (tz == 0)      qws[((size_t)bh * S_ + s) * D_ + dh] = bv;
                else if (tz == 1) kws[((size_t)bh * S_ + s) * D_ + dh] = bv;
                else              vtws[((size_t)bh * D_ + dh) * SP_ + s] = bv;
            }
        }
    }
}

// ---------------------------------------------------------------------------
// Kernel 2: attention. One block per (bh, q-tile); 4 waves own key quarters
// (16/15/15/15 tiles). Pass A per tile, with explicit K/V register
// double-buffer prefetch (next tile's 6 loads issue BEFORE this tile's
// compute): QK^T (K=32, swapped) -> exp -> pack pp[ct] -> PV via K=16 MFMA
// consuming packed registers directly. No LDS in the loop. Pass B: burst of
// normalized NT attn stores from pp. Then olds combine + x epilogue.
// ---------------------------------------------------------------------------
__global__ __launch_bounds__(256) void attn_kernel(
    const short* __restrict__ qws, const short* __restrict__ kws,
    const short* __restrict__ vtws, const float* __restrict__ w_out,
    const float* __restrict__ b_out, float* __restrict__ out) {
    __shared__ float olds[3][16 * OSTR];      // 13 KB
    __shared__ float sums[4][16];

    int w    = threadIdx.x >> 6;
    int lane = threadIdx.x & 63;
    int l16  = lane & 15;
    int g    = lane >> 4;

    // XCD swizzle: xcd = blk%8 hosts bh in {xcd, xcd+8, ..., xcd+56}
    int blk = blockIdx.x;       // 0..3903
    int xcd = blk & 7;
    int j   = blk >> 3;         // 0..487
    int bh  = xcd + 8 * (j / H2_);
    int qt  = j % H2_;          // 0..60
    int s0  = qt * 16;

    int t0 = (w == 0) ? 0 : 16 + (w - 1) * 15;   // 0,16,31,46
    int nt = (w == 0) ? 16 : 15;

    const short* qb = qws + ((size_t)bh * S_ + s0 + l16) * D_ + g * 8;
    bf16x8 q0 = *(const bf16x8*)qb;
    bf16x8 q1 = *(const bf16x8*)(qb + 32);
    const short* kbase = kws + ((size_t)bh * S_ + l16) * D_ + g * 8;
    const short* vbase = vtws + ((size_t)bh * D_ + l16) * SP_ + g * 4;

    unsigned pp[16][2];         // packed bf16 exp-scores (static-indexed)
    f32x4 o0 = {0.f,0.f,0.f,0.f}, o1 = {0.f,0.f,0.f,0.f};
    f32x4 o2 = {0.f,0.f,0.f,0.f}, o3 = {0.f,0.f,0.f,0.f};
    float sa = 0.f, sb = 0.f, sc_ = 0.f, sd = 0.f;

    // prefetch registers (SSA-renamed each iteration)
    bf16x8 nk0, nk1;
    bf16x4 nv0, nv1, nv2, nv3;
    {
        const short* kb = kbase + (size_t)t0 * 16 * D_;
        nk0 = *(const bf16x8*)kb;
        nk1 = *(const bf16x8*)(kb + 32);
        const short* vb = vbase + t0 * 16;
        nv0 = *(const bf16x4*)(vb);
        nv1 = *(const bf16x4*)(vb + 16 * SP_);
        nv2 = *(const bf16x4*)(vb + 32 * SP_);
        nv3 = *(const bf16x4*)(vb + 48 * SP_);
    }

    #pragma unroll
    for (int ct = 0; ct < 16; ++ct) {
        if (ct < nt) {                        // wave-uniform
            bf16x8 k0 = nk0, k1 = nk1;
            bf16x4 v0 = nv0, v1 = nv1, v2 = nv2, v3 = nv3;
            if (ct + 1 < nt) {                // prefetch next tile FIRST
                int gt = t0 + ct + 1;
                const short* kb = kbase + (size_t)gt * 16 * D_;
                nk0 = *(const bf16x8*)kb;
                nk1 = *(const bf16x8*)(kb + 32);
                const short* vb = vbase + gt * 16;
                nv0 = *(const bf16x4*)(vb);
                nv1 = *(const bf16x4*)(vb + 16 * SP_);
                nv2 = *(const bf16x4*)(vb + 32 * SP_);
                nv3 = *(const bf16x4*)(vb + 48 * SP_);
            }
            f32x4 acc = {0.f, 0.f, 0.f, 0.f};
            acc = __builtin_amdgcn_mfma_f32_16x16x32_bf16(k0, q0, acc, 0, 0, 0);
            acc = __builtin_amdgcn_mfma_f32_16x16x32_bf16(k1, q1, acc, 0, 0, 0);
            float e0 = __expf(acc[0] * 0.125f);
            float e1 = __expf(acc[1] * 0.125f);
            float e2 = __expf(acc[2] * 0.125f);
            float e3 = __expf(acc[3] * 0.125f);
            sa += e0; sb += e1; sc_ += e2; sd += e3;
            unsigned u0 = packbf(e0, e1);
            unsigned u1 = packbf(e2, e3);
            pp[ct][0] = u0;
            pp[ct][1] = u1;
            union { uint2 u; bf16x4 v; } pc;
            pc.u.x = u0; pc.u.y = u1;
            o0 = mfma16(pc.v, v0, o0);
            o1 = mfma16(pc.v, v1, o1);
            o2 = mfma16(pc.v, v2, o2);
            o3 = mfma16(pc.v, v3, o3);
        }
    }
    float sum = (sa + sb) + (sc_ + sd);
    sum += __shfl_xor(sum, 16);
    sum += __shfl_xor(sum, 32);
    if (lane < 16) sums[w][l16] = sum;
    __syncthreads();
    float inv = 1.f / ((sums[0][l16] + sums[1][l16]) +
                       (sums[2][l16] + sums[3][l16]));

    // ---- pass B: dependence-free burst of normalized attn stores ----
    float* arow = out + XOFF + ((size_t)bh * S_ + s0 + l16) * S_;
    #pragma unroll
    for (int ct = 0; ct < 16; ++ct) {
        if (ct < nt) {
            unsigned u0 = pp[ct][0], u1 = pp[ct][1];
            f32x4 pv = { bflo(u0) * inv, bfhi(u0) * inv,
                         bflo(u1) * inv, bfhi(u1) * inv };
            __builtin_nontemporal_store(pv,
                (f32x4*)(arow + (t0 + ct) * 16 + g * 4));
        }
    }

    // ---- waves 0..2 publish raw partial O ----
    if (w != 3) {
        float* ob = &olds[w][0];
        #pragma unroll
        for (int i = 0; i < 4; ++i) {
            int q = g * 4 + i;
            ob[q * OSTR +  0 + l16] = o0[i];
            ob[q * OSTR + 16 + l16] = o1[i];
            ob[q * OSTR + 32 + l16] = o2[i];
            ob[q * OSTR + 48 + l16] = o3[i];
        }
    }
    __syncthreads();

    // ---- w3 combines, normalizes (deferred inv), writes x ----
    if (w == 3) {
        float wo = w_out[0], bo = b_out[0];
        int b = bh >> 3, hh = bh & 7;
        #pragma unroll
        for (int i = 0; i < 4; ++i) {
            int q = g * 4 + i;
            float invq = 1.f / ((sums[0][q] + sums[1][q]) +
                                (sums[2][q] + sums[3][q]));
            float s1 = invq * wo;
            float* xr = out + ((size_t)b * S_ + s0 + q) * DM_ + hh * D_ + l16;
            int o = q * OSTR + l16;
            xr[0]  = (o0[i] + olds[0][o +  0] + olds[1][o +  0] + olds[2][o +  0]) * s1 + bo;
            xr[16] = (o1[i] + olds[0][o + 16] + olds[1][o + 16] + olds[2][o + 16]) * s1 + bo;
            xr[32] = (o2[i] + olds[0][o + 32] + olds[1][o + 32] + olds[2][o + 32]) * s1 + bo;
            xr[48] = (o3[i] + olds[0][o + 48] + olds[1][o + 48] + olds[2][o + 48]) * s1 + bo;
        }
    }
}

// ---------------------------------------------------------------------------
extern "C" void kernel_launch(void* const* d_in, const int* in_sizes, int n_in,
                              void* d_out, int out_size, void* d_ws, size_t ws_size,
                              hipStream_t stream) {
    const float* q   = (const float*)d_in[0];
    const float* k   = (const float*)d_in[1];
    const float* v   = (const float*)d_in[2];
    const float* wq  = (const float*)d_in[3];
    const float* wk  = (const float*)d_in[4];
    const float* wv  = (const float*)d_in[5];
    const float* wo  = (const float*)d_in[6];
    const float* bo  = (const float*)d_in[7];

    char* ws = (char*)d_ws;
    short* qws  = (short*)(ws + 196608);
    short* kws  = qws + (size_t)BH_ * S_ * D_;
    short* vtws = kws + (size_t)BH_ * S_ * D_;

    proj_kernel<<<384, 256, 0, stream>>>(q, k, v, wq, wk, wv, qws, kws, vtws);
    attn_kernel<<<BH_ * H2_, 256, 0, stream>>>(qws, kws, vtws, wo, bo,
                                               (float*)d_out);
}

// Round 12
// 165.764 us; speedup vs baseline: 1.1218x; 1.1179x over previous
//
#include <hip/hip_runtime.h>
#include <hip/hip_bf16.h>
#include <cstdint>
#include <cstddef>

// Problem constants
#define B_    8
#define H_    8
#define BH_   64
#define S_    976     // sequence length
#define SP_   992     // V^T row stride (shorts)
#define D_    64      // head dim
#define DM_   512     // d_model
#define L_    16      // max_len
#define H2_   61      // pooled conv height / q-tiles
#define KW_   25      // conv taps
#define EFF_  32      // effective (conv+pool) taps
#define XOFF  3997696 // x output elements = 8*976*512; attn follows
#define OSTR  68      // olds row stride (floats)
#define PWC   132     // per-wave packed-P row stride (u32)

typedef __attribute__((ext_vector_type(8))) short bf16x8;
typedef __attribute__((ext_vector_type(4))) short bf16x4;
typedef __attribute__((ext_vector_type(4))) float f32x4;

__device__ __forceinline__ unsigned short f2bfu(float f) {
    union { float f; unsigned u; } v; v.f = f;
    unsigned u = v.u;
    u += 0x7fffu + ((u >> 16) & 1u);   // round-to-nearest-even
    return (unsigned short)(u >> 16);
}
__device__ __forceinline__ unsigned packbf(float a, float b) {
    return (unsigned)f2bfu(a) | ((unsigned)f2bfu(b) << 16);
}
__device__ __forceinline__ float bflo(unsigned u) {
    union { unsigned u; float f; } v; v.u = u << 16; return v.f;
}
__device__ __forceinline__ float bfhi(unsigned u) {
    union { unsigned u; float f; } v; v.u = u & 0xffff0000u; return v.f;
}

// K=16 bf16 MFMA: A row = lane&15, k = (lane>>4)*4+i; C/D col=lane&15,
// row=(lane>>4)*4+i  (verified end-to-end in round 7)
__device__ __forceinline__ f32x4 mfma16(bf16x4 a, bf16x4 b, f32x4 c) {
#if __has_builtin(__builtin_amdgcn_mfma_f32_16x16x16bf16_1k)
    return __builtin_amdgcn_mfma_f32_16x16x16bf16_1k(a, b, c, 0, 0, 0);
#else
    asm volatile("v_mfma_f32_16x16x16_bf16 %0, %1, %2, %0"
                 : "+v"(c) : "v"(a), "v"(b));
    return c;
#endif
}

// ---------------------------------------------------------------------------
// Kernel 1: projection with inline conv+pool weight folding (unchanged).
// ---------------------------------------------------------------------------
__global__ __launch_bounds__(256) void proj_kernel(
    const float* __restrict__ qin, const float* __restrict__ kin,
    const float* __restrict__ vin, const float* __restrict__ wq,
    const float* __restrict__ wk, const float* __restrict__ wv,
    short* __restrict__ qws, short* __restrict__ kws, short* __restrict__ vtws) {
    __shared__ float xl[536 * L_];   // 34.3 KB
    __shared__ float wl[32 * 32];    // 4 KB folded weights
    int blk = blockIdx.x;            // grid = 3*8*16 = 384
    int cg  = blk & 15;
    int b   = (blk >> 4) & 7;
    int tz  = blk >> 7;
    const float* x    = (tz == 0) ? qin : (tz == 1) ? kin : vin;
    const float* wsrc = (tz == 0) ? wq  : (tz == 1) ? wk  : wv;

    const float4* xb4 = (const float4*)(x + b * DM_ * L_);
    float4* xl4 = (float4*)xl;
    for (int i = threadIdx.x; i < DM_ * L_ / 4; i += 256) xl4[i] = xb4[i];
    for (int i = DM_ * L_ + threadIdx.x; i < 536 * L_; i += 256) xl[i] = 0.f;

    for (int i = threadIdx.x; i < 1024; i += 256) {
        int ci = i >> 5;
        int t  = i & 31;
        int c  = cg * 32 + ci;
        int jlo = (t - 24 > 0) ? t - 24 : 0;
        int jhi = (t < 7) ? t : 7;
        float s = 0.f;
        for (int jj = jlo; jj <= jhi; ++jj) s += wsrc[c * KW_ + (t - jj)];
        wl[i] = s * 0.125f;
    }
    __syncthreads();

    int c_local = threadIdx.x >> 3;
    int plane   = threadIdx.x & 7;
    int c       = cg * 32 + c_local;
    float wreg[EFF_];
    #pragma unroll
    for (int i = 0; i < EFF_; ++i) wreg[i] = wl[c_local * 32 + i];

    for (int m = 0; m < 32; ++m) {
        int pg  = plane + 8 * m;
        int h2b = pg >> 4;
        int l   = pg & 15;
        float acc[4] = {0.f, 0.f, 0.f, 0.f};
        #pragma unroll
        for (int k = 0; k < 56; ++k) {
            float xv = xl[(h2b * 32 + k) * L_ + l];
            #pragma unroll
            for (int d = 0; d < 4; ++d) {
                int t = k - 8 * d;
                if (t >= 0 && t < EFF_) acc[d] = fmaf(xv, wreg[t], acc[d]);
            }
        }
        #pragma unroll
        for (int d = 0; d < 4; ++d) {
            int h2 = h2b * 4 + d;
            if (h2 < H2_) {
                int f    = c * S_ + h2 * L_ + l;
                int s    = f >> 9;
                int head = (f >> 6) & 7;
                int dh   = f & 63;
                int bh   = b * H_ + head;
                short bv = (short)f2bfu(acc[d]);
                if (tz == 0)      qws[((size_t)bh * S_ + s) * D_ + dh] = bv;
                else if (tz == 1) kws[((size_t)bh * S_ + s) * D_ + dh] = bv;
                else              vtws[((size_t)bh * D_ + dh) * SP_ + s] = bv;
            }
        }
    }
}

// ---------------------------------------------------------------------------
// Kernel 2: attention. One block per (bh, q-tile); 4 waves own key quarters
// (16/15/15/15 tiles). Pass A per tile (1-deep K/V register prefetch):
// QK^T (K=32, swapped) -> exp -> pack bf16 -> {ds_write to per-wave P tile,
// PV via K=16 MFMA on the packed registers}. Pass B: per wave, each of the
// 16 attn rows is ONE contiguous 1KB plain store (4 waves tile the 976
// cols; L2 merges full lines -> streaming write efficiency). P-tile LDS is
// reused for the O-combine.
// ---------------------------------------------------------------------------
__global__ __launch_bounds__(256) void attn_kernel(
    const short* __restrict__ qws, const short* __restrict__ kws,
    const short* __restrict__ vtws, const float* __restrict__ w_out,
    const float* __restrict__ b_out, float* __restrict__ out) {
    __shared__ unsigned pw[4][16][PWC];   // 33.8 KB packed P; reused as olds
    __shared__ float sums[4][16];

    int w    = threadIdx.x >> 6;
    int lane = threadIdx.x & 63;
    int l16  = lane & 15;
    int g    = lane >> 4;

    // XCD swizzle: xcd = blk%8 hosts bh in {xcd, xcd+8, ..., xcd+56}
    int blk = blockIdx.x;       // 0..3903
    int xcd = blk & 7;
    int j   = blk >> 3;         // 0..487
    int bh  = xcd + 8 * (j / H2_);
    int qt  = j % H2_;          // 0..60
    int s0  = qt * 16;

    int t0 = (w == 0) ? 0 : 16 + (w - 1) * 15;   // 0,16,31,46
    int nt = (w == 0) ? 16 : 15;

    const short* qb = qws + ((size_t)bh * S_ + s0 + l16) * D_ + g * 8;
    bf16x8 q0 = *(const bf16x8*)qb;
    bf16x8 q1 = *(const bf16x8*)(qb + 32);
    const short* kbase = kws + ((size_t)bh * S_ + l16) * D_ + g * 8;
    const short* vbase = vtws + ((size_t)bh * D_ + l16) * SP_ + g * 4;

    f32x4 o0 = {0.f,0.f,0.f,0.f}, o1 = {0.f,0.f,0.f,0.f};
    f32x4 o2 = {0.f,0.f,0.f,0.f}, o3 = {0.f,0.f,0.f,0.f};
    float sa = 0.f, sb = 0.f, sc_ = 0.f, sd = 0.f;

    // 1-deep K/V register prefetch
    bf16x8 nk0, nk1;
    bf16x4 nv0, nv1, nv2, nv3;
    {
        const short* kb = kbase + (size_t)t0 * 16 * D_;
        nk0 = *(const bf16x8*)kb;
        nk1 = *(const bf16x8*)(kb + 32);
        const short* vb = vbase + t0 * 16;
        nv0 = *(const bf16x4*)(vb);
        nv1 = *(const bf16x4*)(vb + 16 * SP_);
        nv2 = *(const bf16x4*)(vb + 32 * SP_);
        nv3 = *(const bf16x4*)(vb + 48 * SP_);
    }

    #pragma unroll
    for (int ct = 0; ct < 16; ++ct) {
        if (ct < nt) {                        // wave-uniform
            bf16x8 k0 = nk0, k1 = nk1;
            bf16x4 v0 = nv0, v1 = nv1, v2 = nv2, v3 = nv3;
            if (ct + 1 < nt) {                // prefetch next tile FIRST
                int gt = t0 + ct + 1;
                const short* kb = kbase + (size_t)gt * 16 * D_;
                nk0 = *(const bf16x8*)kb;
                nk1 = *(const bf16x8*)(kb + 32);
                const short* vb = vbase + gt * 16;
                nv0 = *(const bf16x4*)(vb);
                nv1 = *(const bf16x4*)(vb + 16 * SP_);
                nv2 = *(const bf16x4*)(vb + 32 * SP_);
                nv3 = *(const bf16x4*)(vb + 48 * SP_);
            }
            f32x4 acc = {0.f, 0.f, 0.f, 0.f};
            acc = __builtin_amdgcn_mfma_f32_16x16x32_bf16(k0, q0, acc, 0, 0, 0);
            acc = __builtin_amdgcn_mfma_f32_16x16x32_bf16(k1, q1, acc, 0, 0, 0);
            float e0 = __expf(acc[0] * 0.125f);
            float e1 = __expf(acc[1] * 0.125f);
            float e2 = __expf(acc[2] * 0.125f);
            float e3 = __expf(acc[3] * 0.125f);
            sa += e0; sb += e1; sc_ += e2; sd += e3;
            unsigned u0 = packbf(e0, e1);
            unsigned u1 = packbf(e2, e3);
            uint2 pk2 = {u0, u1};
            *(uint2*)(void*)&pw[w][l16][ct * 8 + g * 2] = pk2;
            union { uint2 u; bf16x4 v; } pc;
            pc.u.x = u0; pc.u.y = u1;
            o0 = mfma16(pc.v, v0, o0);
            o1 = mfma16(pc.v, v1, o1);
            o2 = mfma16(pc.v, v2, o2);
            o3 = mfma16(pc.v, v3, o3);
        }
    }
    float sum = (sa + sb) + (sc_ + sd);
    sum += __shfl_xor(sum, 16);
    sum += __shfl_xor(sum, 32);
    if (lane < 16) sums[w][l16] = sum;
    __syncthreads();

    // ---- pass B: contiguous per-row attn stores (this wave's col range) ----
    {
        int colbase = t0 * 16;                // 0,256,496,736
        int ncol_u  = nt * 8;                 // packed u32 per row: 128 / 120
        bool act = (lane * 2) < ncol_u;       // w0: all 64; w1-3: lane<60
        float* abase = out + XOFF + ((size_t)bh * S_ + s0) * S_ + colbase + lane * 4;
        #pragma unroll
        for (int r = 0; r < 16; ++r) {
            float invr = 1.f / ((sums[0][r] + sums[1][r]) +
                                (sums[2][r] + sums[3][r]));
            if (act) {
                uint2 raw = *(const uint2*)(void*)&pw[w][r][lane * 2];
                f32x4 pv = { bflo(raw.x) * invr, bfhi(raw.x) * invr,
                             bflo(raw.y) * invr, bfhi(raw.y) * invr };
                *(f32x4*)(abase + (size_t)r * S_) = pv;   // 1KB contiguous/row
            }
        }
    }
    __syncthreads();                           // pw reads done; reuse as olds

    // ---- waves 0..2 publish raw partial O (olds aliases pw) ----
    float* olds = (float*)&pw[0][0][0];
    if (w != 3) {
        float* ob = olds + w * 16 * OSTR;
        #pragma unroll
        for (int i = 0; i < 4; ++i) {
            int q = g * 4 + i;
            ob[q * OSTR +  0 + l16] = o0[i];
            ob[q * OSTR + 16 + l16] = o1[i];
            ob[q * OSTR + 32 + l16] = o2[i];
            ob[q * OSTR + 48 + l16] = o3[i];
        }
    }
    __syncthreads();

    // ---- w3 combines, normalizes (deferred inv), writes x ----
    if (w == 3) {
        float wo = w_out[0], bo = b_out[0];
        int b = bh >> 3, hh = bh & 7;
        #pragma unroll
        for (int i = 0; i < 4; ++i) {
            int q = g * 4 + i;
            float invq = 1.f / ((sums[0][q] + sums[1][q]) +
                                (sums[2][q] + sums[3][q]));
            float s1 = invq * wo;
            float* xr = out + ((size_t)b * S_ + s0 + q) * DM_ + hh * D_ + l16;
            int o = q * OSTR + l16;
            xr[0]  = (o0[i] + olds[o +  0] + olds[16*OSTR + o +  0] + olds[32*OSTR + o +  0]) * s1 + bo;
            xr[16] = (o1[i] + olds[o + 16] + olds[16*OSTR + o + 16] + olds[32*OSTR + o + 16]) * s1 + bo;
            xr[32] = (o2[i] + olds[o + 32] + olds[16*OSTR + o + 32] + olds[32*OSTR + o + 32]) * s1 + bo;
            xr[48] = (o3[i] + olds[o + 48] + olds[16*OSTR + o + 48] + olds[32*OSTR + o + 48]) * s1 + bo;
        }
    }
}

// ---------------------------------------------------------------------------
extern "C" void kernel_launch(void* const* d_in, const int* in_sizes, int n_in,
                              void* d_out, int out_size, void* d_ws, size_t ws_size,
                              hipStream_t stream) {
    const float* q   = (const float*)d_in[0];
    const float* k   = (const float*)d_in[1];
    const float* v   = (const float*)d_in[2];
    const float* wq  = (const float*)d_in[3];
    const float* wk  = (const float*)d_in[4];
    const float* wv  = (const float*)d_in[5];
    const float* wo  = (const float*)d_in[6];
    const float* bo  = (const float*)d_in[7];

    char* ws = (char*)d_ws;
    short* qws  = (short*)(ws + 196608);
    short* kws  = qws + (size_t)BH_ * S_ * D_;
    short* vtws = kws + (size_t)BH_ * S_ * D_;

    proj_kernel<<<384, 256, 0, stream>>>(q, k, v, wq, wk, wv, qws, kws, vtws);
    attn_kernel<<<BH_ * H2_, 256, 0, stream>>>(qws, kws, vtws, wo, bo,
                                               (float*)d_out);
}